// Round 10
// baseline (19549.254 us; speedup 1.0000x reference)
//
#include <hip/hip_runtime.h>

// ACT RNN, T=8192, IO=32, H=256, M=4, EPS=0.01. All f32 in/out.
// Round 18: barrier-width experiment. Accounting gap: at 2.4 GHz the measured
// 1.45us/timestep = ~3480cy but the instr/chain model explains ~800-1200cy.
// Only un-modeled candidate: s_barrier cost scaling with participant count
// (8 waves, 2 barriers/timestep; never isolated). This round: 4 waves x
// (4 rows x 64 cols)/lane — per-SIMD VALU issue IDENTICAL, LDS read instrs
// halved, publish/halting/reduce chains identical, but each barrier syncs
// 4 waves instead of 8. wt[4][32] v2f = 256 VGPR, ~370 total, under the
// 450-spill line with __launch_bounds__(256,1).
// Algebra byte-identical to the verified round-15/17 body (11.755 ms,
// absmax 1.95e-3): Z-linearity, branchless rounds 0-1 + rare uniform rounds
// 2-3, quad xor1+xor2 reduce, 8-deep fma chains, plds hoist, 2-deep U ring,
// L2E prefolds, lgkmcnt-only barrier.
// ws = 8.45 MB (AccS aliases U in place; ws_size 16 MiB).

#define T_  8192
#define IO_ 32
#define H_  256

typedef __attribute__((ext_vector_type(2))) float v2f;
typedef __attribute__((ext_vector_type(4))) float v4f;

template<int CTRL>
__device__ __forceinline__ float dpp_addf(float x) {
    int xi = __builtin_bit_cast(int, x);
    int d = __builtin_amdgcn_update_dpp(xi, xi, CTRL, 0xF, 0xF, false);
    return x + __builtin_bit_cast(float, d);
}
// LDS-only barrier: flush DS ops, sync, do NOT drain vmcnt (global prefetch
// and fire-and-forget stores stay in flight).
__device__ __forceinline__ void bar_lds() {
    asm volatile("s_waitcnt lgkmcnt(0)\n\ts_barrier" ::: "memory");
    __builtin_amdgcn_sched_barrier(0);
}

// ---------------- k_prep: WxpT[io][h] = (Wx[:,:H]@Wp)^T, c = Wx[:,:H]@bp + b
__global__ void k_prep(const float* __restrict__ Wx,
                       const float* __restrict__ Wp,
                       const float* __restrict__ bp,
                       const float* __restrict__ b,
                       float* __restrict__ WxpT, float* __restrict__ cvec) {
    int h = blockIdx.x;           // 0..255
    int t = threadIdx.x;          // 0..63
    __shared__ float wxrow[H_];
    for (int j = t; j < H_; j += 64) wxrow[j] = Wx[h * (H_ + 1) + j];
    __syncthreads();
    if (t < IO_) {
        float acc = 0.0f;
        for (int j = 0; j < H_; ++j) acc += wxrow[j] * Wp[j * IO_ + t];
        WxpT[t * H_ + h] = acc;
    } else if (t == IO_) {
        float acc = b[h];
        for (int j = 0; j < H_; ++j) acc += wxrow[j] * bp[j];
        cvec[h] = acc;
    }
}

// ---------------- k_u: U[t][h] = (WxpT^T x_t + c) * 2*log2(e) ----------------
__global__ void k_u(const float* __restrict__ x,
                    const float* __restrict__ WxpT,
                    const float* __restrict__ cvec,
                    float* __restrict__ U) {
    int t0 = blockIdx.x * 8;
    int tid = threadIdx.x;        // 256
    __shared__ float xsf[8 * IO_];
    xsf[tid] = x[(size_t)t0 * IO_ + tid];
    __syncthreads();
    int h = tid;
    float base = cvec[h];
    const float L2E2 = 2.8853900817779268f;
    for (int tt = 0; tt < 8; ++tt) {
        float acc = base;
        #pragma unroll
        for (int io = 0; io < IO_; ++io)
            acc += WxpT[io * H_ + h] * xsf[tt * IO_ + io];
        U[(size_t)(t0 + tt) * H_ + h] = acc * L2E2;
    }
}

// ---------------- act_chain: 4 waves, 4 rows x 64 cols per lane ------------
__global__ __launch_bounds__(256, 1) void act_chain(
    const float* __restrict__ Ws,
    const float* __restrict__ Wx,
    const float* __restrict__ wh,
    const float* __restrict__ bh1,
    const float* __restrict__ h0,
    float* __restrict__ UAcc,
    float* __restrict__ cumArr,
    float* __restrict__ pc_out)
{
    __shared__ __align__(16) float sbuf[2][4 * 68];
    __shared__ __align__(16) float plds[2][8];

    const int tid = threadIdx.x;
    const int w   = tid >> 6;        // wave 0..3
    const int l   = tid & 63;
    const int rg  = l >> 2;          // row-group 0..15 (4 rows each)
    const int c   = l & 3;           // 64-col chunk 0..3
    const int rowbase = w * 64 + rg * 4;
    // publish target: rows rowbase..rowbase+3 live in chunk w at offset rg*4
    const int pubidx = w * 68 + rg * 4;

    const float L2E  = 1.4426950408889634f;   // log2(e)
    const float L2E2 = 2.8853900817779268f;   // 2*log2(e)

    // Ws tile: 4 rows x 64 cols as v2f[4][32] = 256 VGPR, prescaled
    v2f wt[4][32];
    #pragma unroll
    for (int r = 0; r < 4; ++r) {
        const v4f* src = (const v4f*)(Ws + (size_t)(rowbase + r) * H_ + c * 64);
        #pragma unroll
        for (int q = 0; q < 16; ++q) {
            v4f f = src[q];
            wt[r][2 * q]     = (v2f){f[0] * L2E2, f[1] * L2E2};
            wt[r][2 * q + 1] = (v2f){f[2] * L2E2, f[3] * L2E2};
        }
    }

    v4f wl4, whp4;
    #pragma unroll
    for (int r = 0; r < 4; ++r) {
        wl4[r]  = Wx[(size_t)(rowbase + r) * (H_ + 1) + H_] * L2E2;  // flag wt
        whp4[r] = wh[rowbase + r] * (-L2E);                           // prescale
    }
    const float bhp = -bh1[0] * L2E;
    const float thresh = 1.0f - 0.01f;

    // matvec of a 64-float column chunk + quad reduce. 16 accumulators
    // (4 per row): 8-deep dependent-fma chain, as round 15.
    auto matvec = [&](const v4f* sp) -> v4f {
        v2f acc[4][4];
        #pragma unroll
        for (int r = 0; r < 4; ++r)
            #pragma unroll
            for (int a = 0; a < 4; ++a) acc[r][a] = (v2f){0.f, 0.f};
        #pragma unroll
        for (int q = 0; q < 16; ++q) {
            v4f f = sp[q];
            v2f sa = (v2f){f[0], f[1]};
            v2f sb = (v2f){f[2], f[3]};
            #pragma unroll
            for (int r = 0; r < 4; ++r) {
                acc[r][q & 1]       = acc[r][q & 1]       + wt[r][2 * q]     * sa;
                acc[r][2 + (q & 1)] = acc[r][2 + (q & 1)] + wt[r][2 * q + 1] * sb;
            }
        }
        v4f y;
        #pragma unroll
        for (int r = 0; r < 4; ++r) {
            v2f t = (acc[r][0] + acc[r][1]) + (acc[r][2] + acc[r][3]);
            float yy = t.x + t.y;
            yy = dpp_addf<0xB1>(yy);   // quad xor1
            yy = dpp_addf<0x4E>(yy);   // quad xor2 -> full row sum
            y[r] = yy;
        }
        return y;
    };

    // prologue: zh = scaled Ws @ h0 (chunk read direct from global)
    v4f zh;
    {
        v4f hbuf[16];
        const v4f* hp = (const v4f*)(h0 + c * 64);
        #pragma unroll
        for (int q = 0; q < 16; ++q) hbuf[q] = hp[q];
        zh = matvec(hbuf);
    }

    float pc = 0.0f;
    // 2-deep U prefetch ring
    v4f un  = *(const v4f*)(UAcc + rowbase);
    v4f un1 = *(const v4f*)(UAcc + H_ + rowbase);
    v4f uw0 = un + wl4;                       // round-0 input add, precomputed

    // one ponder round: s = tanh(in); publish; halting partial; barrier;
    // plds read first (halt chain overlaps matvec); matvec(s) -> z.
    auto round = [&](int WB, int PP, v4f in, v4f& z, float& p) -> v4f {
        v4f s;
        #pragma unroll
        for (int i = 0; i < 4; ++i) {
            float e = __builtin_amdgcn_exp2f(in[i]);
            s[i] = __builtin_fmaf(-2.0f, __builtin_amdgcn_rcpf(e + 1.0f), 1.0f);
        }
        if (c == 0) *(v4f*)(&sbuf[WB][pubidx]) = s;
        // halting partial (quad-uniform, 4 rows/lane): ror4+ror8 sum the 16
        // row-groups pairwise along each 16-lane row, bcast15+bcast31 chain
        // rows -> lane63 = wave total (verified chain, round 8)
        float part = (whp4[0] * s[0] + whp4[1] * s[1]) +
                     (whp4[2] * s[2] + whp4[3] * s[3]);
        part = dpp_addf<0x124>(part);   // row_ror:4
        part = dpp_addf<0x128>(part);   // row_ror:8
        part = dpp_addf<0x142>(part);   // row_bcast15
        part = dpp_addf<0x143>(part);   // row_bcast31
        if (l == 63) plds[PP][w] = part;
        bar_lds();
        v4f pa = *(const v4f*)(&plds[PP][0]);           // issue before matvec
        float dot = (pa[0] + pa[1]) + (pa[2] + pa[3]);  // 4 waves
        p = __builtin_amdgcn_rcpf(1.0f + __builtin_amdgcn_exp2f(dot + bhp));
        z = matvec((const v4f*)(&sbuf[WB][c * 68]));
        return s;
    };

    #pragma unroll 1
    for (int t = 0; t < T_; ++t) {
        const int tn2 = (t + 2 < T_) ? t + 2 : T_ - 1;
        const v4f un2 = *(const v4f*)(UAcc + (size_t)tn2 * H_ + rowbase);

        // rounds 0,1 unconditional straight-line
        v4f z0, z1;
        float p0, p1;
        v4f s0 = round(0, 0, zh + uw0, z0, p0);
        v4f s1 = round(1, 1, z0 + un,  z1, p1);

        bool  halt0  = p0 > thresh;
        float w0     = halt0 ? 1.0f : p0;
        bool  still1 = !halt0;
        float cum1   = w0;
        bool  halt1  = (cum1 + p1 > thresh);
        float w1     = still1 ? (halt1 ? 1.0f - cum1 : p1) : 0.0f;
        v4f   accs   = w0 * s0 + w1 * s1;
        v4f   zacc   = w0 * z0 + w1 * z1;
        float cum    = cum1 + w1;
        float nup    = still1 ? 2.0f : 1.0f;
        float rem    = halt0 ? 1.0f : (halt1 ? 1.0f - cum1 : 0.0f);

        if (still1 && !halt1) {               // rare, block-uniform: rounds 2,3
            v4f z2, z3;
            float p2, p3;
            v4f s2 = round(0, 0, z1 + un, z2, p2);
            bool  halt2 = (cum + p2 > thresh);
            float w2    = halt2 ? 1.0f - cum : p2;
            float rem2  = halt2 ? 1.0f - cum : 0.0f;
            accs = accs + w2 * s2;
            zacc = zacc + w2 * z2;
            float cum3   = cum + w2;
            bool  still3 = !halt2;
            v4f s3 = round(1, 1, z2 + un, z3, p3);
            float w3 = still3 ? (1.0f - cum3) : 0.0f;   // n==3 forces halt
            accs = accs + w3 * s3;
            zacc = zacc + w3 * z3;
            rem  = rem2 + w3;
            cum  = cum3 + w3;
            nup  = still3 ? 4.0f : 3.0f;
        }

        pc = (pc + nup + rem) * (1.0f / (float)T_);
        zh = zacc;                            // Z(h') by linearity — no LDS trip
        if (c == 0) *(v4f*)(UAcc + (size_t)t * H_ + rowbase) = accs;
        if (tid == 0) cumArr[t] = cum;
        un  = un1;                            // advance prefetch ring
        un1 = un2;
        uw0 = un + wl4;                       // next round-0 add, off-path
    }
    if (tid == 0) pc_out[0] = pc;
}

// ---------------- k_out: ys[t] = Wo@acc_s[t] + cum[t]*bo ----------------
__global__ void k_out(const float* __restrict__ AccS,
                      const float* __restrict__ Wo,
                      const float* __restrict__ bo,
                      const float* __restrict__ cumArr,
                      float* __restrict__ ys) {
    int t0 = blockIdx.x * 8;
    int tid = threadIdx.x;   // 256
    __shared__ float wo[IO_ * 257];
    __shared__ float as[8 * 260];
    for (int i = tid; i < IO_ * H_; i += 256) {
        int o = i / H_, h = i % H_;
        wo[o * 257 + h] = Wo[i];
    }
    for (int i = tid; i < 8 * H_; i += 256) {
        int tt = i / H_, h = i % H_;
        as[tt * 260 + h] = AccS[(size_t)t0 * H_ + i];
    }
    __syncthreads();
    int tt = tid >> 5, o = tid & 31;
    float acc = cumArr[t0 + tt] * bo[o];
    #pragma unroll 4
    for (int h = 0; h < H_; ++h) acc += wo[o * 257 + h] * as[tt * 260 + h];
    ys[(size_t)(t0 + tt) * IO_ + o] = acc;
}

extern "C" void kernel_launch(void* const* d_in, const int* in_sizes, int n_in,
                              void* d_out, int out_size, void* d_ws, size_t ws_size,
                              hipStream_t stream) {
    const float* x  = (const float*)d_in[0];
    const float* h0 = (const float*)d_in[1];
    const float* Wp = (const float*)d_in[2];
    const float* bp = (const float*)d_in[3];
    const float* Wx = (const float*)d_in[4];
    const float* Ws = (const float*)d_in[5];
    const float* b  = (const float*)d_in[6];
    const float* wh = (const float*)d_in[7];
    const float* bh = (const float*)d_in[8];
    const float* Wo = (const float*)d_in[9];
    const float* bo = (const float*)d_in[10];
    float* out = (float*)d_out;   // f32: ys[8192*32] then pc

    char* ws = (char*)d_ws;
    float* WxpT = (float*)ws;                                    //  32 KB
    float* cvec = (float*)(ws + 32768);                          //   1 KB
    float* cumA = (float*)(ws + 33792);                          //  32 KB
    float* UAcc = (float*)(ws + 66560);                          //   8 MB f32
    // total ws use: 8.45 MB (AccS aliases UAcc in place)

    k_prep<<<H_, 64, 0, stream>>>(Wx, Wp, bp, b, WxpT, cvec);
    k_u<<<T_ / 8, 256, 0, stream>>>(x, WxpT, cvec, UAcc);
    act_chain<<<1, 256, 0, stream>>>(Ws, Wx, wh, bh, h0, UAcc, cumA,
                                     out + (size_t)T_ * IO_);
    k_out<<<T_ / 8, 256, 0, stream>>>(UAcc, Wo, bo, cumA, out);
}

// Round 11
// 11836.186 us; speedup vs baseline: 1.6517x; 1.6517x over previous
//
#include <hip/hip_runtime.h>

// ACT RNN, T=8192, IO=32, H=256, M=4, EPS=0.01. All f32 in/out.
// Round 19: FINAL revert to the round-15 measured-best body (11.755 ms,
// reproduced 11.80 ms in round 17).
// Round-18 post-mortem: 4-wave repartition spilled the 256-VGPR weight tile
// (VGPR_Count 172 + scratch) AND lost the co-resident wave per SIMD that
// hides LDS/chain latency (VALUBusy 0.243 -> 0.166) -> 19.5 ms. The 8-wave /
// 2-rows x 64-cols / 2-waves-per-SIMD configuration is a verified local
// optimum along every probed axis: LDS traffic (4x range: flat), barriers
// (3->2: ~-1%), fma chain (32->8: ~-2%), branchless (flat), sigmoid-free
// halt (-1.4% regress), DVFS heaters (no effect), wave count (4: -65%),
// reduce style (quad-DPP best).
// Features: 2-row x 64-col lanes, quad xor1+xor2 reduce, Z-linearity (no h
// publication; 2 barriers/timestep), quad-acc matvec (8-deep chain), plds
// read hoisted before matvec, 2-deep U prefetch ring, L2E prefolds,
// lgkmcnt-only barrier, branchless rounds 0-1 + rare uniform rounds 2-3.
// ws = 8.45 MB (AccS aliases U in place; ws_size 16 MiB).

#define T_  8192
#define IO_ 32
#define H_  256

typedef __attribute__((ext_vector_type(2))) float v2f;

template<int CTRL>
__device__ __forceinline__ float dpp_addf(float x) {
    int xi = __builtin_bit_cast(int, x);
    int d = __builtin_amdgcn_update_dpp(xi, xi, CTRL, 0xF, 0xF, false);
    return x + __builtin_bit_cast(float, d);
}
// LDS-only barrier: flush DS ops, sync, do NOT drain vmcnt (global prefetch
// and fire-and-forget stores stay in flight).
__device__ __forceinline__ void bar_lds() {
    asm volatile("s_waitcnt lgkmcnt(0)\n\ts_barrier" ::: "memory");
    __builtin_amdgcn_sched_barrier(0);
}

// ---------------- k_prep: WxpT[io][h] = (Wx[:,:H]@Wp)^T, c = Wx[:,:H]@bp + b
__global__ void k_prep(const float* __restrict__ Wx,
                       const float* __restrict__ Wp,
                       const float* __restrict__ bp,
                       const float* __restrict__ b,
                       float* __restrict__ WxpT, float* __restrict__ cvec) {
    int h = blockIdx.x;           // 0..255
    int t = threadIdx.x;          // 0..63
    __shared__ float wxrow[H_];
    for (int j = t; j < H_; j += 64) wxrow[j] = Wx[h * (H_ + 1) + j];
    __syncthreads();
    if (t < IO_) {
        float acc = 0.0f;
        for (int j = 0; j < H_; ++j) acc += wxrow[j] * Wp[j * IO_ + t];
        WxpT[t * H_ + h] = acc;
    } else if (t == IO_) {
        float acc = b[h];
        for (int j = 0; j < H_; ++j) acc += wxrow[j] * bp[j];
        cvec[h] = acc;
    }
}

// ---------------- k_u: U[t][h] = (WxpT^T x_t + c) * 2*log2(e) ----------------
__global__ void k_u(const float* __restrict__ x,
                    const float* __restrict__ WxpT,
                    const float* __restrict__ cvec,
                    float* __restrict__ U) {
    int t0 = blockIdx.x * 8;
    int tid = threadIdx.x;        // 256
    __shared__ float xsf[8 * IO_];
    xsf[tid] = x[(size_t)t0 * IO_ + tid];
    __syncthreads();
    int h = tid;
    float base = cvec[h];
    const float L2E2 = 2.8853900817779268f;
    for (int tt = 0; tt < 8; ++tt) {
        float acc = base;
        #pragma unroll
        for (int io = 0; io < IO_; ++io)
            acc += WxpT[io * H_ + h] * xsf[tt * IO_ + io];
        U[(size_t)(t0 + tt) * H_ + h] = acc * L2E2;
    }
}

// ---------------- act_chain ----------------
__global__ __launch_bounds__(512, 2) void act_chain(
    const float* __restrict__ Ws,
    const float* __restrict__ Wx,
    const float* __restrict__ wh,
    const float* __restrict__ bh1,
    const float* __restrict__ h0,
    float* __restrict__ UAcc,
    float* __restrict__ cumArr,
    float* __restrict__ pc_out)
{
    __shared__ __align__(16) float sbuf[2][4 * 68];
    __shared__ __align__(16) float plds[2][8];

    const int tid = threadIdx.x;
    const int w   = tid >> 6;        // wave 0..7
    const int l   = tid & 63;
    const int rg  = l >> 2;          // row-group 0..15 (2 rows each)
    const int c   = l & 3;           // 64-col chunk 0..3
    const int rowbase = w * 32 + rg * 2;
    const int schunk  = rowbase >> 6;
    const int soff    = rowbase & 63;

    const float L2E  = 1.4426950408889634f;   // log2(e)
    const float L2E2 = 2.8853900817779268f;   // 2*log2(e)

    // Ws tile: 2 rows x 64 cols as v2f[2][32], prescaled by 2*log2(e)
    v2f wt[2][32];
    #pragma unroll
    for (int r = 0; r < 2; ++r) {
        const float4* src = (const float4*)(Ws + (size_t)(rowbase + r) * H_ + c * 64);
        #pragma unroll
        for (int q = 0; q < 16; ++q) {
            float4 f = src[q];
            wt[r][2 * q]     = (v2f){f.x * L2E2, f.y * L2E2};
            wt[r][2 * q + 1] = (v2f){f.z * L2E2, f.w * L2E2};
        }
    }

    v2f wl2, whp2;
    wl2.x  = Wx[(size_t)rowbase * (H_ + 1) + H_] * L2E2;       // first-step flag
    wl2.y  = Wx[(size_t)(rowbase + 1) * (H_ + 1) + H_] * L2E2;
    whp2.x = wh[rowbase]     * (-L2E);                          // sigmoid prescale
    whp2.y = wh[rowbase + 1] * (-L2E);
    const float bhp = -bh1[0] * L2E;
    const float thresh = 1.0f - 0.01f;

    // matvec of a 64-float column chunk + quad reduce.
    // Quad accumulators per row: 8-deep dependent-fma chain.
    auto matvec = [&](const float4* sp) -> v2f {
        v2f a0[4] = {{0.f,0.f},{0.f,0.f},{0.f,0.f},{0.f,0.f}};
        v2f a1[4] = {{0.f,0.f},{0.f,0.f},{0.f,0.f},{0.f,0.f}};
        #pragma unroll
        for (int q = 0; q < 16; ++q) {
            float4 f = sp[q];
            v2f sa = (v2f){f.x, f.y};
            v2f sb = (v2f){f.z, f.w};
            a0[q & 1]       = a0[q & 1]       + wt[0][2 * q]     * sa;
            a0[2 + (q & 1)] = a0[2 + (q & 1)] + wt[0][2 * q + 1] * sb;
            a1[q & 1]       = a1[q & 1]       + wt[1][2 * q]     * sa;
            a1[2 + (q & 1)] = a1[2 + (q & 1)] + wt[1][2 * q + 1] * sb;
        }
        v2f t0 = (a0[0] + a0[1]) + (a0[2] + a0[3]);
        v2f t1 = (a1[0] + a1[1]) + (a1[2] + a1[3]);
        float y0 = t0.x + t0.y;
        float y1 = t1.x + t1.y;
        y0 = dpp_addf<0xB1>(y0); y0 = dpp_addf<0x4E>(y0);   // quad xor1, xor2
        y1 = dpp_addf<0xB1>(y1); y1 = dpp_addf<0x4E>(y1);
        return (v2f){y0, y1};
    };

    // prologue: zh = scaled Ws @ h0 (chunk read direct from global)
    v2f zh;
    {
        float4 hbuf[16];
        const float4* hp = (const float4*)(h0 + c * 64);
        #pragma unroll
        for (int q = 0; q < 16; ++q) hbuf[q] = hp[q];
        zh = matvec(hbuf);
    }

    float pc = 0.0f;
    // 2-deep U prefetch ring
    v2f un  = *(const v2f*)(UAcc + rowbase);
    v2f un1 = *(const v2f*)(UAcc + (T_ > 1 ? H_ : 0) + rowbase);
    v2f uw0 = un + wl2;                       // round-0 input add, precomputed

    // one ponder round: s = tanh(in); publish; halting partial; barrier;
    // plds read first (halt chain overlaps matvec); matvec(s) -> z.
    auto round = [&](int WB, int PP, v2f in, v2f& z, float& p) -> v2f {
        float e0 = __builtin_amdgcn_exp2f(in.x);
        float e1 = __builtin_amdgcn_exp2f(in.y);
        float s0 = __builtin_fmaf(-2.0f, __builtin_amdgcn_rcpf(e0 + 1.0f), 1.0f);
        float s1 = __builtin_fmaf(-2.0f, __builtin_amdgcn_rcpf(e1 + 1.0f), 1.0f);
        if (c == 0) *(v2f*)(&sbuf[WB][schunk * 68 + soff]) = (v2f){s0, s1};
        // halting partial (quad-uniform): ror4+ror8 over row-groups,
        // bcast15+bcast31 -> lane63 = wave total (verified round 8)
        float part = __builtin_fmaf(whp2.x, s0, whp2.y * s1);
        part = dpp_addf<0x124>(part);   // row_ror:4
        part = dpp_addf<0x128>(part);   // row_ror:8
        part = dpp_addf<0x142>(part);   // row_bcast15
        part = dpp_addf<0x143>(part);   // row_bcast31
        if (l == 63) plds[PP][w] = part;
        bar_lds();
        float4 pa = *(const float4*)(&plds[PP][0]);     // issue before matvec
        float4 pb = *(const float4*)(&plds[PP][4]);     // reads: halt chain
        float dot = ((pa.x + pa.y) + (pa.z + pa.w)) +   // overlaps matvec
                    ((pb.x + pb.y) + (pb.z + pb.w));
        p = __builtin_amdgcn_rcpf(1.0f + __builtin_amdgcn_exp2f(dot + bhp));
        z = matvec((const float4*)(&sbuf[WB][c * 68]));
        return (v2f){s0, s1};
    };

    #pragma unroll 1
    for (int t = 0; t < T_; ++t) {
        const int tn2 = (t + 2 < T_) ? t + 2 : T_ - 1;
        const v2f un2 = *(const v2f*)(UAcc + (size_t)tn2 * H_ + rowbase);

        // rounds 0,1 unconditional straight-line
        v2f z0, z1;
        float p0, p1;
        v2f s0 = round(0, 0, zh + uw0, z0, p0);
        v2f s1 = round(1, 1, z0 + un,  z1, p1);

        bool  halt0  = p0 > thresh;
        float w0     = halt0 ? 1.0f : p0;
        bool  still1 = !halt0;
        float cum1   = w0;
        bool  halt1  = (cum1 + p1 > thresh);
        float w1     = still1 ? (halt1 ? 1.0f - cum1 : p1) : 0.0f;
        v2f   accs   = w0 * s0 + w1 * s1;
        v2f   zacc   = w0 * z0 + w1 * z1;
        float cum    = cum1 + w1;
        float nup    = still1 ? 2.0f : 1.0f;
        float rem    = halt0 ? 1.0f : (halt1 ? 1.0f - cum1 : 0.0f);

        if (still1 && !halt1) {               // rare, block-uniform: rounds 2,3
            v2f z2, z3;
            float p2, p3;
            v2f s2 = round(0, 0, z1 + un, z2, p2);
            bool  halt2 = (cum + p2 > thresh);
            float w2    = halt2 ? 1.0f - cum : p2;
            float rem2  = halt2 ? 1.0f - cum : 0.0f;
            accs = accs + w2 * s2;
            zacc = zacc + w2 * z2;
            float cum3   = cum + w2;
            bool  still3 = !halt2;
            v2f s3 = round(1, 1, z2 + un, z3, p3);
            float w3 = still3 ? (1.0f - cum3) : 0.0f;   // n==3 forces halt
            accs = accs + w3 * s3;
            zacc = zacc + w3 * z3;
            rem  = rem2 + w3;
            cum  = cum3 + w3;
            nup  = still3 ? 4.0f : 3.0f;
        }

        pc = (pc + nup + rem) * (1.0f / (float)T_);
        zh = zacc;                            // Z(h') by linearity — no LDS trip
        if (c == 0) *(v2f*)(UAcc + (size_t)t * H_ + rowbase) = accs;
        if (tid == 0) cumArr[t] = cum;
        un  = un1;                            // advance prefetch ring
        un1 = un2;
        uw0 = un + wl2;                       // next round-0 add, off-path
    }
    if (tid == 0) pc_out[0] = pc;
}

// ---------------- k_out: ys[t] = Wo@acc_s[t] + cum[t]*bo ----------------
__global__ void k_out(const float* __restrict__ AccS,
                      const float* __restrict__ Wo,
                      const float* __restrict__ bo,
                      const float* __restrict__ cumArr,
                      float* __restrict__ ys) {
    int t0 = blockIdx.x * 8;
    int tid = threadIdx.x;   // 256
    __shared__ float wo[IO_ * 257];
    __shared__ float as[8 * 260];
    for (int i = tid; i < IO_ * H_; i += 256) {
        int o = i / H_, h = i % H_;
        wo[o * 257 + h] = Wo[i];
    }
    for (int i = tid; i < 8 * H_; i += 256) {
        int tt = i / H_, h = i % H_;
        as[tt * 260 + h] = AccS[(size_t)t0 * H_ + i];
    }
    __syncthreads();
    int tt = tid >> 5, o = tid & 31;
    float acc = cumArr[t0 + tt] * bo[o];
    #pragma unroll 4
    for (int h = 0; h < H_; ++h) acc += wo[o * 257 + h] * as[tt * 260 + h];
    ys[(size_t)(t0 + tt) * IO_ + o] = acc;
}

extern "C" void kernel_launch(void* const* d_in, const int* in_sizes, int n_in,
                              void* d_out, int out_size, void* d_ws, size_t ws_size,
                              hipStream_t stream) {
    const float* x  = (const float*)d_in[0];
    const float* h0 = (const float*)d_in[1];
    const float* Wp = (const float*)d_in[2];
    const float* bp = (const float*)d_in[3];
    const float* Wx = (const float*)d_in[4];
    const float* Ws = (const float*)d_in[5];
    const float* b  = (const float*)d_in[6];
    const float* wh = (const float*)d_in[7];
    const float* bh = (const float*)d_in[8];
    const float* Wo = (const float*)d_in[9];
    const float* bo = (const float*)d_in[10];
    float* out = (float*)d_out;   // f32: ys[8192*32] then pc

    char* ws = (char*)d_ws;
    float* WxpT = (float*)ws;                                    //  32 KB
    float* cvec = (float*)(ws + 32768);                          //   1 KB
    float* cumA = (float*)(ws + 33792);                          //  32 KB
    float* UAcc = (float*)(ws + 66560);                          //   8 MB f32
    // total ws use: 8.45 MB (AccS aliases UAcc in place)

    k_prep<<<H_, 64, 0, stream>>>(Wx, Wp, bp, b, WxpT, cvec);
    k_u<<<T_ / 8, 256, 0, stream>>>(x, WxpT, cvec, UAcc);
    act_chain<<<1, 512, 0, stream>>>(Ws, Wx, wh, bh, h0, UAcc, cumA,
                                     out + (size_t)T_ * IO_);
    k_out<<<T_ / 8, 256, 0, stream>>>(UAcc, Wo, bo, cumA, out);
}